// Round 1
// 190.045 us; speedup vs baseline: 1.0492x; 1.0492x over previous
//
#include <hip/hip_runtime.h>

// BatchBlur via bf16 MFMA banded-Toeplitz. R5 = R4 with staging overhaul:
//  - 228 threads own fixed col-quads; reflect-x + col math hoisted out of loop
//  - all 52 slab loads issued into registers up front (one latency exposure,
//    sk staging overlaps the in-flight loads)
//  - f32->bf16 via v_cvt_pk_bf16_f32 (RNE, bit-identical to old f2bf funnel)
//  - __launch_bounds__(256,6): LDS 26112B fits 6 blocks/CU (156672<=163840)
// MFMA loop / layouts unchanged from R4 (verified):
// A: m=lane&15,k=q*8+j ; B: n=lane&15,k=q*8+j ; D: n=lane&15, m=q*4+reg.

#define HH 512
#define WW 512
#define LL 15
#define PP 7
#define TW 128
#define TH 64
#define SH (TH + LL - 1)          // 78
#define SWB 152                   // slab row in bf16 elems; 304B rows, 16B-aligned
#define KPAD 64                   // kernel row pad (128B)
#define NSEG 8
#define NROWIT 13                 // 78 rows / 6 row-starts

typedef __attribute__((ext_vector_type(8))) short bf16x8;
typedef __attribute__((ext_vector_type(4))) float f32x4;

__device__ inline unsigned short f2bf(float f) {
    unsigned u = __builtin_bit_cast(unsigned, f);
    return (unsigned short)((u + 0x7fffu + ((u >> 16) & 1u)) >> 16);   // RNE
}

__device__ inline unsigned cvt_pk_bf16(float lo, float hi) {
    unsigned r;
    asm("v_cvt_pk_bf16_f32 %0, %1, %2" : "=v"(r) : "v"(lo), "v"(hi));
    return r;
}

__global__ __launch_bounds__(256, 6)
void batchblur_mfma(const float* __restrict__ x,
                    const float* __restrict__ kern,
                    float* __restrict__ out)
{
    __shared__ unsigned short sx[SH * SWB];   // 23712 B
    __shared__ unsigned short sk[LL * KPAD];  // 1920 B

    const int tid   = threadIdx.x;
    const int ox0   = blockIdx.x * TW;
    const int oy0   = blockIdx.y * TH;
    const int plane = blockIdx.z;
    const int b     = plane / 3;

    const float* __restrict__ xp = x + (size_t)plane * (HH * WW);
    const float* __restrict__ kp = kern + b * (LL * LL);

    // ---- sx staging, phase 1: issue ALL global loads into registers ----
    // 228 active threads = 38 col-quads x 6 row-starts; 13 row-iters each.
    const bool act = tid < 228;
    int r0 = 0, c4 = 0;
    int gx[4];
    float vv[NROWIT][4];
    if (act) {
        r0 = tid / 38;                 // 0..5 (magic-mul, once)
        c4 = (tid - r0 * 38) * 4;      // 0..148
        #pragma unroll
        for (int j = 0; j < 4; ++j) {
            int g = ox0 + c4 + j - PP;
            gx[j] = g < 0 ? -g : (g >= WW ? 2 * WW - 2 - g : g);
        }
        #pragma unroll
        for (int k = 0; k < NROWIT; ++k) {
            int gy = oy0 + (r0 + 6 * k) - PP;
            gy = gy < 0 ? -gy : (gy >= HH ? 2 * HH - 2 - gy : gy);
            const float* __restrict__ rowp = xp + (size_t)gy * WW;
            #pragma unroll
            for (int j = 0; j < 4; ++j) vv[k][j] = rowp[gx[j]];
        }
    }

    // ---- stage zero-padded kernel rows (bf16) while sx loads are in flight ----
    for (int i = tid; i < LL * KPAD; i += 256) {
        int ky = i >> 6, c = i & 63;
        float v = (c >= 16 && c < 16 + LL) ? kp[ky * LL + (c - 16)] : 0.f;
        sk[i] = f2bf(v);
    }

    // ---- sx staging, phase 2: convert (packed RNE) + ds_write_b64 ----
    if (act) {
        #pragma unroll
        for (int k = 0; k < NROWIT; ++k) {
            int r = r0 + 6 * k;
            uint2 pk;
            pk.x = cvt_pk_bf16(vv[k][0], vv[k][1]);
            pk.y = cvt_pk_bf16(vv[k][2], vv[k][3]);
            *(uint2*)&sx[r * SWB + c4] = pk;
        }
    }
    __syncthreads();

    const int lane = tid & 63;
    const int t    = lane & 15;       // A row m / B-D col n
    const int q    = lane >> 4;       // quad
    const int g    = tid >> 6;        // wave -> 16-row group
    const int rowbase = g * 16 + t;

    f32x4 acc[NSEG];
    #pragma unroll
    for (int s = 0; s < NSEG; ++s) acc[s] = (f32x4){0.f, 0.f, 0.f, 0.f};

    // A-build geometry (loop-invariant): elements e..e+7 of padded kernel row.
    // byte offset b0 = 2e is even; align to 4B so funnel shift is 0 or 16 bits.
    const int e    = 16 + q * 8 - t;  // in [1, 40]
    const int b0   = 2 * e;           // in [2, 80]
    const int base = (b0 & ~3) >> 2;  // dword index, in [0, 20]; base+4 <= 24 < 32
    const int sh   = (b0 & 3) * 8;    // 0 or 16

    #pragma unroll 1
    for (int ky = 0; ky < LL; ++ky) {
        // ---- banded A fragment via 4B-aligned reads + 32-bit funnels ----
        const int* rp = (const int*)&sk[ky * KPAD];
        int v[5];
        #pragma unroll
        for (int j = 0; j < 5; ++j) v[j] = rp[base + j];
        int r32[4];
        #pragma unroll
        for (int j = 0; j < 4; ++j)
            r32[j] = (int)(unsigned)(((((unsigned long long)(unsigned)v[j + 1]) << 32)
                                      | (unsigned)v[j]) >> sh);
        bf16x8 afrag = __builtin_bit_cast(bf16x8, (int4){r32[0], r32[1], r32[2], r32[3]});

        const unsigned short* srow = &sx[(rowbase + ky) * SWB + q * 8];
        // ---- 8 segments, two groups of 4 to bound live B-frags ----
        bf16x8 bf[4];
        #pragma unroll
        for (int s = 0; s < 4; ++s) bf[s] = *(const bf16x8*)&srow[s * 16];
        #pragma unroll
        for (int s = 0; s < 4; ++s)
            acc[s] = __builtin_amdgcn_mfma_f32_16x16x32_bf16(afrag, bf[s], acc[s], 0, 0, 0);
        #pragma unroll
        for (int s = 0; s < 4; ++s) bf[s] = *(const bf16x8*)&srow[(s + 4) * 16];
        #pragma unroll
        for (int s = 0; s < 4; ++s)
            acc[s + 4] = __builtin_amdgcn_mfma_f32_16x16x32_bf16(afrag, bf[s], acc[s + 4], 0, 0, 0);
    }

    // ---- store: 8 x float4, D layout n=lane&15 (row), m=q*4+reg (col) ----
    float* __restrict__ op = out + (size_t)plane * (HH * WW) + (size_t)(oy0 + rowbase) * WW + ox0;
    #pragma unroll
    for (int s = 0; s < NSEG; ++s) {
        float* dst = op + s * 16 + q * 4;
        *(float4*)dst = make_float4(acc[s][0], acc[s][1], acc[s][2], acc[s][3]);
    }
}

extern "C" void kernel_launch(void* const* d_in, const int* in_sizes, int n_in,
                              void* d_out, int out_size, void* d_ws, size_t ws_size,
                              hipStream_t stream) {
    const float* x  = (const float*)d_in[0];
    const float* kn = (const float*)d_in[1];
    float* out      = (float*)d_out;
    dim3 grid(WW / TW, HH / TH, 32 * 3);   // (4, 8, 96)
    batchblur_mfma<<<grid, dim3(256), 0, stream>>>(x, kn, out);
}